// Round 11
// baseline (1337.267 us; speedup 1.0000x reference)
//
#include <hip/hip_runtime.h>
#include <math.h>

#define HWs 6400

typedef __attribute__((ext_vector_type(8))) short s8v;
typedef __attribute__((ext_vector_type(4))) float f4v;
typedef unsigned short ushortT;
typedef unsigned int uintT;

__device__ __forceinline__ float sigm_(float x){ return 1.0f/(1.0f+__expf(-x)); }
__device__ __forceinline__ float silu_(float x){ return x/(1.0f+__expf(-x)); }
__device__ __forceinline__ ushortT f2bf(float f){
  uintT u = __float_as_uint(f);
  u = (u + 0x7fffu + ((u>>16)&1u)) >> 16;
  return (ushortT)u;
}

// ---------------- weight prep ----------------
// pad16=1: k = c*16 + r (r<9 real, 9..15 zero), K = Cin*16
// pad16=0: k = r*Cin + c (r-major, for DCN)
__global__ void wtb_kernel(const float* __restrict__ w, ushortT* __restrict__ Bt,
                           int lcin, int OC, int Npad, int K, int pad16){
  int idx = blockIdx.x*256 + threadIdx.x;
  if (idx >= Npad*K) return;
  int n = idx / K, k = idx - n*K;
  float v = 0.0f;
  if (n < OC){
    if (pad16){
      int c = k >> 4, r = k & 15;
      if (r < 9) v = w[(((size_t)n << lcin) + c)*9 + r];
    } else {
      int r = k >> lcin, c = k & ((1<<lcin)-1);
      v = w[(((size_t)n << lcin) + c)*9 + r];
    }
  }
  Bt[idx] = f2bf(v);
}

// ---------------- bn scale/shift prep ----------------
// layout: [0:16] sc1 [16:32] sh1 [32:48] sc2 [48:64] sh2 [64:192] scF [192:320] shF
__global__ void bnprep_kernel(const float* __restrict__ bn1, const float* __restrict__ bn2,
                              const float* __restrict__ bnf, float* __restrict__ o){
  int t = threadIdx.x;
  if (t < 16){
    float s = bn1[t] / sqrtf(bn1[48+t] + 1e-5f);
    o[t] = s; o[16+t] = bn1[16+t] - bn1[32+t]*s;
  } else if (t < 32){
    int i = t-16;
    float s = bn2[i] / sqrtf(bn2[48+i] + 1e-5f);
    o[32+i] = s; o[48+i] = bn2[16+i] - bn2[32+i]*s;
  } else if (t < 160){
    int i = t-32;
    float s = bnf[i] / sqrtf(bnf[384+i] + 1e-5f);
    o[64+i] = s; o[192+i] = bnf[128+i] - bnf[256+i]*s;
  }
}

// ---------------- MFMA implicit-GEMM conv ----------------
// BM=64, BK=32, 256 thr = 4 waves. Grid = 800. Batch=XCD map: b = bid&7, tile = bid>>3.
// BN=128: waves 2x2, wave tile 32x64 (MF=2,NF=4). BN=32: waves 4x1, tile 16x32.
// MODE 0/2: k = c*16 + r (taps inner, padded to 16; compile-time tap decode).
//   Thread (sm, kg): cg=kg>>1 selects channel (c0+cg), hi=kg&1 selects r 0..7 / 8..15.
//   MODE 2 scales sampled value by g (c<Cin0) or 1-g (c>=Cin0), g sampled at tap position.
// MODE 1: k = r*128 + c (r-major), deformable bilinear gather; per-XCD L2 holds one batch.
// EPI: 0 +bias ; 1 silu(x+bias) ; 2 silu(x*sc+sh) ; 3 silu(x*sc+sh)+rs*res
template<int MODE, int BN, int EPI, int LCIN>
__global__ __launch_bounds__(256,4)
void mconv(const float* __restrict__ A0, const float* __restrict__ A1,
           int Cin0,
           const float* __restrict__ offp,
           const ushortT* __restrict__ Bt, int K,
           float* __restrict__ Out, int Nout,
           const float* __restrict__ e0, const float* __restrict__ e1,
           const float* __restrict__ res, const float* __restrict__ rsp)
{
  constexpr int CINM = (1<<LCIN) - 1;
  constexpr int MF = (BN==128)? 2 : 1;
  constexpr int NF = (BN==128)? 4 : 2;
  constexpr int BCH = (BN==128)? 2 : 1;
  __shared__ ushortT As[64*40];
  __shared__ ushortT Bs[BN*40];

  const int tid = threadIdx.x;
  const int bid = blockIdx.x;
  const int b   = bid & 7;             // batch = XCD (round-robin dispatch)
  const int pt  = (bid >> 3) * 64;     // tile origin within batch plane
  const int sm  = tid & 63;
  const int kg  = tid >> 6;            // wave-uniform 0..3
  const int cg  = kg >> 1;             // channel-in-pair (MODE0/2)
  const int hi  = kg & 1;              // tap half (MODE0/2)
  const int p   = pt + sm;
  const int y   = p / 80;
  const int x   = p - y*80;

  const float* base0 = A0 + (size_t)b*Cin0*HWs;
  const float* base1 = (MODE!=1)? (A1 + ((size_t)b*((1<<LCIN)-Cin0) - (size_t)Cin0)*HWs) : A0;
  const float* gb    = (MODE==2)? (offp + (size_t)b*HWs) : A0;
  const float* ofb   = (MODE==1)? (offp + (size_t)b*27*HWs + p) : A0;
  const float* irb   = A0 + (size_t)b*128*HWs;

  // compute ids
  const int ln  = tid & 63;
  const int l15 = ln & 15, lg = ln >> 4;
  const int wv  = tid >> 6;
  const int wmb = (BN==128)? ((wv>>1)*32) : (wv*16);
  const int wnb = (BN==128)? ((wv&1)*64) : 0;

  f4v acc[MF][NF];
  #pragma unroll
  for (int i=0;i<MF;i++)
    #pragma unroll
    for (int j=0;j<NF;j++)
      #pragma unroll
      for (int q=0;q<4;q++) acc[i][j][q] = 0.0f;

  // MODE1 cached bilinear state
  float w00=0.f,w01=0.f,w10=0.f,w11=0.f;
  int o00=0,o01=0,o10=0,o11=0;

  for (int k0 = 0; k0 < K; k0 += 32){
    s8v h;
    if (MODE != 1){
      const int c = (k0 >> 4) + cg;
      const float* plane = ((c < Cin0)? base0 : base1) + (size_t)c*HWs;
      if (hi == 0){
        #pragma unroll
        for (int kk=0; kk<8; kk++){
          const int dyc = kk/3 - 1;
          const int dxc = kk - (kk/3)*3 - 1;
          const bool v = ((unsigned)(y+dyc) < 80u) & ((unsigned)(x+dxc) < 80u);
          const int pp = v ? (p + dyc*80 + dxc) : 0;
          float val = plane[pp];
          if (MODE == 2){
            float gv = gb[pp];
            val *= (c < Cin0)? gv : (1.0f - gv);
          }
          h[kk] = (short)(v ? f2bf(val) : (ushortT)0);
        }
      } else {
        const bool v = ((unsigned)(y+1) < 80u) & ((unsigned)(x+1) < 80u);
        const int pp = v ? (p + 81) : 0;
        float val = plane[pp];
        if (MODE == 2){
          float gv = gb[pp];
          val *= (c < Cin0)? gv : (1.0f - gv);
        }
        h[0] = (short)(v ? f2bf(val) : (ushortT)0);
        #pragma unroll
        for (int kk=1; kk<8; kk++) h[kk] = 0;
      }
    } else {
      const int kb = k0 + kg*8;
      const int r  = kb >> 7;          // wave-uniform tap
      const int c0 = kb & 127;
      if ((k0 & 127) == 0){            // r changed -> recompute bilinear state
        float oy = ofb[(size_t)(2*r)*HWs];
        float ox = ofb[(size_t)(2*r+1)*HWs];
        float mk = sigm_(ofb[(size_t)(18+r)*HWs]);
        int r3 = r/3;
        int dy = r3, dx = r - r3*3;
        float ys = oy + (float)(y + dy - 1);
        float xs = ox + (float)(x + dx - 1);
        float yf = floorf(ys), xf = floorf(xs);
        float wy = ys - yf, wx = xs - xf;
        int y0 = (int)yf, x0 = (int)xf;
        float vy0 = ((unsigned)y0     < 80u)? 1.f : 0.f;
        float vy1 = ((unsigned)(y0+1) < 80u)? 1.f : 0.f;
        float vx0 = ((unsigned)x0     < 80u)? 1.f : 0.f;
        float vx1 = ((unsigned)(x0+1) < 80u)? 1.f : 0.f;
        w00 = (1.f-wy)*(1.f-wx)*mk*vy0*vx0;
        w01 = (1.f-wy)*wx      *mk*vy0*vx1;
        w10 = wy      *(1.f-wx)*mk*vy1*vx0;
        w11 = wy      *wx      *mk*vy1*vx1;
        int cy0 = min(max(y0  ,0),79), cy1 = min(max(y0+1,0),79);
        int cx0 = min(max(x0  ,0),79), cx1 = min(max(x0+1,0),79);
        o00 = cy0*80+cx0; o01 = cy0*80+cx1; o10 = cy1*80+cx0; o11 = cy1*80+cx1;
      }
      const float* q00 = irb + (size_t)c0*HWs + o00;
      const float* q01 = irb + (size_t)c0*HWs + o01;
      const float* q10 = irb + (size_t)c0*HWs + o10;
      const float* q11 = irb + (size_t)c0*HWs + o11;
      #pragma unroll
      for (int kk=0;kk<8;kk++){
        float val = w00*q00[(size_t)kk*HWs] + w01*q01[(size_t)kk*HWs]
                  + w10*q10[(size_t)kk*HWs] + w11*q11[(size_t)kk*HWs];
        h[kk] = (short)f2bf(val);
      }
    }

    // B chunk loads (bf16 global -> regs)
    uint4 bchunk[BCH];
    #pragma unroll
    for (int i=0;i<BCH;i++){
      int ch = tid + i*256;
      if (BN==128 || tid < 128){
        int n = ch >> 2, kc = (ch & 3) << 3;
        bchunk[i] = *(const uint4*)(Bt + (size_t)n*K + k0 + kc);
      }
    }

    __syncthreads();
    *(s8v*)&As[sm*40 + kg*8] = h;
    #pragma unroll
    for (int i=0;i<BCH;i++){
      int ch = tid + i*256;
      if (BN==128 || tid < 128){
        int n = ch >> 2, kc = (ch & 3) << 3;
        *(uint4*)&Bs[n*40 + kc] = bchunk[i];
      }
    }
    __syncthreads();

    // fragments + MFMA
    s8v af[MF], bfr[NF];
    #pragma unroll
    for (int i=0;i<MF;i++) af[i]  = *(const s8v*)&As[(wmb + i*16 + l15)*40 + lg*8];
    #pragma unroll
    for (int j=0;j<NF;j++) bfr[j] = *(const s8v*)&Bs[(wnb + j*16 + l15)*40 + lg*8];
    #pragma unroll
    for (int i=0;i<MF;i++)
      #pragma unroll
      for (int j=0;j<NF;j++)
        acc[i][j] = __builtin_amdgcn_mfma_f32_16x16x32_bf16(af[i], bfr[j], acc[i][j], 0, 0, 0);
    __syncthreads();
  }

  // epilogue: lane holds rows 4*lg..+3 (consecutive m), col = l15
  float rsv = (EPI==3)? rsp[0] : 0.0f;
  #pragma unroll
  for (int i=0;i<MF;i++){
    int p0 = pt + wmb + i*16 + 4*lg;
    #pragma unroll
    for (int j=0;j<NF;j++){
      int n = wnb + j*16 + l15;
      if (BN==32 && n >= Nout) continue;
      size_t ob = ((size_t)b*Nout + n)*HWs + p0;
      float vv[4];
      #pragma unroll
      for (int q=0;q<4;q++) vv[q] = acc[i][j][q];
      if (EPI == 0){
        float bb = e0[n];
        #pragma unroll
        for (int q=0;q<4;q++) vv[q] += bb;
      } else if (EPI == 1){
        float bb = e0[n];
        #pragma unroll
        for (int q=0;q<4;q++) vv[q] = silu_(vv[q] + bb);
      } else if (EPI == 2){
        float s = e0[n], sh = e1[n];
        #pragma unroll
        for (int q=0;q<4;q++) vv[q] = silu_(fmaf(vv[q], s, sh));
      } else {
        float s = e0[n], sh = e1[n];
        float4 r4 = *(const float4*)(res + ob);
        float rr[4] = {r4.x, r4.y, r4.z, r4.w};
        #pragma unroll
        for (int q=0;q<4;q++) vv[q] = silu_(fmaf(vv[q], s, sh)) + rsv*rr[q];
      }
      float4 o4; o4.x=vv[0]; o4.y=vv[1]; o4.z=vv[2]; o4.w=vv[3];
      *(float4*)(Out + ob) = o4;
    }
  }
}

// ---------------- gate conv1x1 256->16 + bn + silu ----------------
__global__ __launch_bounds__(256) void gate1_kernel(
  const float* __restrict__ rgb, const float* __restrict__ iral,
  const float* __restrict__ wg1, const float* __restrict__ bns,
  float* __restrict__ out)
{
  __shared__ float Ws[4096];   // [c][mc]
  int tid = threadIdx.x;
  for (int i = tid; i < 4096; i += 256){
    int mc = i >> 8, c = i & 255;
    Ws[c*16 + mc] = wg1[i];
  }
  __syncthreads();
  int idx = blockIdx.x*256 + tid;
  int b = idx / HWs, p = idx - b*HWs;
  const float* r0 = rgb  + (size_t)b*128*HWs + p;
  const float* i0 = iral + ((size_t)b*128 - 128)*HWs + p;
  float acc[16];
  #pragma unroll
  for (int mc=0;mc<16;mc++) acc[mc]=0.f;
  #pragma unroll 4
  for (int c=0;c<256;c++){
    float v = (c<128) ? r0[(size_t)c*HWs] : i0[(size_t)c*HWs];
    const float4* w4 = (const float4*)&Ws[c*16];
    #pragma unroll
    for (int q=0;q<4;q++){
      float4 w = w4[q];
      acc[q*4+0] = fmaf(v, w.x, acc[q*4+0]);
      acc[q*4+1] = fmaf(v, w.y, acc[q*4+1]);
      acc[q*4+2] = fmaf(v, w.z, acc[q*4+2]);
      acc[q*4+3] = fmaf(v, w.w, acc[q*4+3]);
    }
  }
  #pragma unroll
  for (int mc=0;mc<16;mc++){
    float t = fmaf(acc[mc], bns[mc], bns[16+mc]);
    out[((size_t)b*16+mc)*HWs + p] = silu_(t);
  }
}

// ---------------- gate depthwise3x3+bn+silu + conv1x1->1 + sigmoid ----------------
__global__ __launch_bounds__(256) void gate23_kernel(
  const float* __restrict__ g1b, const float* __restrict__ wg2,
  const float* __restrict__ wg3, const float* __restrict__ bg3,
  const float* __restrict__ bns, float* __restrict__ g)
{
  __shared__ float w2s[144], w3s[16], sc2[16], sh2[16];
  __shared__ float b3s;
  int tid = threadIdx.x;
  if (tid < 144) w2s[tid] = wg2[tid];
  if (tid < 16){ w3s[tid] = wg3[tid]; sc2[tid] = bns[32+tid]; sh2[tid] = bns[48+tid]; }
  if (tid == 0) b3s = bg3[0];
  __syncthreads();
  int idx = blockIdx.x*256 + tid;
  int b = idx / HWs, p = idx - b*HWs;
  int y = p/80, x = p - y*80;
  float acc = b3s;
  #pragma unroll
  for (int mc=0;mc<16;mc++){
    const float* base = g1b + ((size_t)b*16+mc)*HWs;
    float s = 0.f;
    #pragma unroll
    for (int r=0;r<9;r++){
      int dy = r/3, dx = r - (r/3)*3;
      int yy = y + dy - 1, xx = x + dx - 1;
      if (((unsigned)yy < 80u) & ((unsigned)xx < 80u))
        s = fmaf(base[yy*80+xx], w2s[mc*9+r], s);
    }
    float t = fmaf(s, sc2[mc], sh2[mc]);
    acc = fmaf(silu_(t), w3s[mc], acc);
  }
  g[idx] = sigm_(acc);
}

extern "C" void kernel_launch(void* const* d_in, const int* in_sizes, int n_in,
                              void* d_out, int out_size, void* d_ws, size_t ws_size,
                              hipStream_t stream)
{
  const float* rgb  = (const float*)d_in[0];
  const float* ir   = (const float*)d_in[1];
  const float* w1   = (const float*)d_in[2];
  const float* b1   = (const float*)d_in[3];
  const float* w2   = (const float*)d_in[4];
  const float* b2   = (const float*)d_in[5];
  const float* wd   = (const float*)d_in[6];
  const float* bd   = (const float*)d_in[7];
  const float* wg1  = (const float*)d_in[8];
  const float* bng1 = (const float*)d_in[9];
  const float* wg2  = (const float*)d_in[10];
  const float* bng2 = (const float*)d_in[11];
  const float* wg3  = (const float*)d_in[12];
  const float* bg3  = (const float*)d_in[13];
  const float* wf   = (const float*)d_in[14];
  const float* bnf  = (const float*)d_in[15];
  const float* rs   = (const float*)d_in[16];
  float* out = (float*)d_out;

  float* ws   = (float*)d_ws;
  float* hbuf = ws;                    // 6,553,600 f
  float* offb = hbuf + 6553600;        // 1,382,400 f
  float* iral = offb + 1382400;        // 6,553,600 f
  float* g1b  = iral + 6553600;        //   819,200 f
  float* gbuf = g1b  + 819200;         //    51,200 f
  float* bns  = gbuf + 51200;          //       320 f
  ushortT* Bt1 = (ushortT*)(bns + 320);        // 128*4096 (pad16)
  ushortT* Bt2 = Bt1 + 524288;                 //  32*2048 (pad16)
  ushortT* Bt3 = Bt2 + 65536;                  // 128*1152 (r-major)
  ushortT* Bt4 = Bt3 + 147456;                 // 128*4096 (pad16)
  // total ~64 MB

  bnprep_kernel<<<1, 256, 0, stream>>>(bng1, bng2, bnf, bns);
  wtb_kernel<<<(524288+255)/256, 256, 0, stream>>>(w1, Bt1, 8, 128, 128, 4096, 1);
  wtb_kernel<<<( 65536+255)/256, 256, 0, stream>>>(w2, Bt2, 7,  27,  32, 2048, 1);
  wtb_kernel<<<(147456+255)/256, 256, 0, stream>>>(wd, Bt3, 7, 128, 128, 1152, 0);
  wtb_kernel<<<(524288+255)/256, 256, 0, stream>>>(wf, Bt4, 8, 128, 128, 4096, 1);

  // h = silu(conv3x3(cat(rgb,ir), w_off1) + b_off1)
  mconv<0,128,1,8><<<800, 256, 0, stream>>>(rgb, ir, 128, nullptr,
      Bt1, 4096, hbuf, 128, b1, nullptr, nullptr, nullptr);
  // off = conv3x3(h, w_off2) + b_off2   (27 ch raw)
  mconv<0,32,0,7><<<800, 256, 0, stream>>>(hbuf, hbuf, 128, nullptr,
      Bt2, 2048, offb, 27, b2, nullptr, nullptr, nullptr);
  // ir_aligned = DCN(ir, offsets, mask) + b_dcn   (fused bilinear gather)
  mconv<1,128,0,7><<<800, 256, 0, stream>>>(ir, ir, 128, offb,
      Bt3, 1152, iral, 128, bd, nullptr, nullptr, nullptr);
  // gate path
  gate1_kernel<<<200, 256, 0, stream>>>(rgb, iral, wg1, bns, g1b);
  gate23_kernel<<<200, 256, 0, stream>>>(g1b, wg2, wg3, bg3, bns, gbuf);
  // out = silu(bn(conv3x3(concat(g*ir_al,(1-g)*rgb), w_f))) + res_scale*ir_aligned
  mconv<2,128,3,8><<<800, 256, 0, stream>>>(iral, rgb, 128, gbuf,
      Bt4, 4096, out, 128, bns+64, bns+192, iral, rs);
}